// Round 10
// baseline (165.679 us; speedup 1.0000x reference)
//
#include <hip/hip_runtime.h>

typedef unsigned short u16;
typedef unsigned int u32;
typedef __attribute__((ext_vector_type(2))) unsigned int u32x2;
typedef __attribute__((ext_vector_type(4))) unsigned int u32x4;
typedef __attribute__((ext_vector_type(4))) unsigned short u16x4;
typedef __attribute__((ext_vector_type(8))) unsigned short u16x8;
typedef __attribute__((ext_vector_type(8))) short short8;
typedef __attribute__((ext_vector_type(4))) float f32x4;
typedef __attribute__((ext_vector_type(16))) float f32x16;

#define NHEAD 16
#define HDIM 64
#define SEQ 2048
#define MODELD 1024
#define MROWS 4096            // B*N
#define QKVCOLS 3072
// ATT_SCALE * log2(e), folded into q weights/bias so softmax uses exp2
#define QSCALE 0.18033688011112042f

#define WAITVM(N) asm volatile("s_waitcnt vmcnt(" #N ")" ::: "memory")

__device__ __forceinline__ u16 f2bf(float f) {
  union { float f; unsigned u; } v; v.f = f;
  unsigned r = v.u + 0x7FFFu + ((v.u >> 16) & 1u);
  return (u16)(r >> 16);
}

// packed f32x2 -> bf16x2 (RTNE), single instruction (T12)
__device__ __forceinline__ u32 cvtpk(float lo, float hi) {
  u32 r;
  asm("v_cvt_pk_bf16_f32 %0, %1, %2" : "=v"(r) : "v"(lo), "v"(hi));
  return r;
}

// v_permlane32_swap: a' = [a.lo32lanes | b.lo32lanes], b' = [a.hi | b.hi]
__device__ __forceinline__ void pl32(u32& a, u32& b) {
  asm("v_permlane32_swap_b32 %0, %1" : "+v"(a), "+v"(b));
}

__device__ __forceinline__ void gload_lds16(const void* g, void* l) {
  __builtin_amdgcn_global_load_lds((const __attribute__((address_space(1))) void*)g,
                                   (__attribute__((address_space(3))) void*)l, 16, 0, 0);
}

// ---------------- prep kernels ----------------

// f32 -> bf16, 4 elems/thread, exact grid
__global__ void prep_cast(const float* __restrict__ in, u16* __restrict__ outb) {
  int i = blockIdx.x * 256 + threadIdx.x;
  float4 v = *(const float4*)(in + (size_t)i * 4);
  u16x4 o = {f2bf(v.x), f2bf(v.y), f2bf(v.z), f2bf(v.w)};
  *(u16x4*)(outb + (size_t)i * 4) = o;
}

// mask -> bf16 {1.0, 0.0}; parallel int32-vs-byte marshalling probe. 1x1024x4 = 4096.
__global__ void prep_mask(const unsigned int* __restrict__ mraw, u16* __restrict__ mbf) {
  __shared__ int flag;
  const int tid = threadIdx.x;
  if (tid == 0) flag = 0;
  __syncthreads();
  if (mraw[tid] > 1u) flag = 1;   // race-benign
  __syncthreads();
  const int is_bytes = flag;
  const unsigned char* bp = (const unsigned char*)mraw;
  u16x4 o;
#pragma unroll
  for (int j = 0; j < 4; ++j) {
    unsigned v = is_bytes ? (unsigned)bp[tid * 4 + j] : mraw[tid * 4 + j];
    o[j] = v ? (u16)0x3F80 : (u16)0;
  }
  *(u16x4*)(mbf + tid * 4) = o;
}

// write K-ext chunk (ks=4) into frag-major K: k=64 component = mask ? 0 : -256(bf16)
// grid (32 tiles, 32 bh), 128 threads
__global__ void mask_ext(const u16* __restrict__ mbf, u16* __restrict__ kfr) {
  const int tile = blockIdx.x, bh = blockIdx.y;
  const int tid = threadIdx.x;
  const int kvblk = tid >> 6, lane = tid & 63;
  const int b = bh >> 4;
  u16x8 o = {};
  if (lane < 32) {
    const int kv = tile * 64 + kvblk * 32 + lane;
    o[0] = mbf[b * SEQ + kv] ? (u16)0 : (u16)0xC380;   // bf16 -256
  }
  *(u16x8*)(kfr + ((size_t)(bh * 32 + tile)) * 5120 + kvblk * 2560 + 2048 + lane * 8) = o;
}

// combined qkv weight (bf16) with LoRA + base fold; q rows pre-scaled by ATT_SCALE*log2e
__global__ void prep_w(const float* __restrict__ wqkv,
                       const float* __restrict__ wqb, const float* __restrict__ bq,
                       const float* __restrict__ wqA, const float* __restrict__ wqB,
                       const float* __restrict__ wvb, const float* __restrict__ bv,
                       const float* __restrict__ wvA, const float* __restrict__ wvB,
                       u16* __restrict__ wcomb, float* __restrict__ biasc) {
  const int c = blockIdx.x;             // 0..3071
  const int t = c >> 10, hd = c & 1023;
  const int k0 = threadIdx.x * 4;
  float4 w = *(const float4*)(wqkv + (size_t)c * MODELD + k0);
  float a0 = w.x, a1 = w.y, a2 = w.z, a3 = w.w;
  if (t != 1) {
    const float* base = (t == 0 ? wqb : wvb) + (size_t)hd * MODELD + k0;
    const float* A = (t == 0 ? wqA : wvA);
    const float* Bm = (t == 0 ? wqB : wvB) + hd * 10;
    float4 bsv = *(const float4*)base;
    a0 += bsv.x; a1 += bsv.y; a2 += bsv.z; a3 += bsv.w;
#pragma unroll
    for (int j = 0; j < 10; ++j) {
      float bj = Bm[j] * 0.1f;               // LORA_SCALE = 1/R
      float4 av = *(const float4*)(A + (size_t)j * MODELD + k0);
      a0 += bj * av.x; a1 += bj * av.y; a2 += bj * av.z; a3 += bj * av.w;
    }
    if (t == 0) { a0 *= QSCALE; a1 *= QSCALE; a2 *= QSCALE; a3 *= QSCALE; }
  }
  u16x4 o = {f2bf(a0), f2bf(a1), f2bf(a2), f2bf(a3)};
  *(u16x4*)(wcomb + (size_t)c * MODELD + k0) = o;
  if (threadIdx.x == 0)
    biasc[c] = (t == 0) ? QSCALE * bq[hd] : ((t == 2) ? bv[hd] : 0.f);
}

// ---------------- 128x128 bf16 MFMA GEMM, BK=64, swizzled LDS ----------------
// MODE 0: scatter q row-major, k/v FRAGMENT-MAJOR (K tile = 5120 u16 incl ext chunk);
// MODE 1: f32 + bias
template<int MODE>
__global__ __launch_bounds__(256) void gemm128(const u16* __restrict__ A, const u16* __restrict__ W,
                                               const float* __restrict__ bias,
                                               u16* __restrict__ oq, u16* __restrict__ ok, u16* __restrict__ ov,
                                               float* __restrict__ of) {
  __shared__ __align__(16) char lds[32768];
  const int tid = threadIdx.x;
  const int lane = tid & 63;
  const int wid = tid >> 6;
  const int wr = wid >> 1, wc = wid & 1;
  const int m0 = blockIdx.y << 7;
  const int n0 = blockIdx.x << 7;
  const int K = MODELD;

  f32x4 acc[4][4] = {};

  const int so = wid * 1024 + (lane << 4);
  for (int kt = 0; kt < K; kt += 64) {
#pragma unroll
    for (int c = 0; c < 4; ++c) {
      const int o = c * 4096 + so;
      const int row = o >> 7;
      const int colb = (o & 127) ^ ((row & 7) << 4);   // inverse-swizzled global source (m173)
      gload_lds16((const char*)(A + (size_t)(m0 + row) * K + kt) + colb, lds + (c * 4096 + wid * 1024));
      gload_lds16((const char*)(W + (size_t)(n0 + row) * K + kt) + colb, lds + (16384 + c * 4096 + wid * 1024));
    }
    __syncthreads();
#pragma unroll
    for (int ks = 0; ks < 2; ++ks) {
      short8 av[4], bv[4];
#pragma unroll
      for (int i = 0; i < 4; ++i) {
        const int arow = wr * 64 + i * 16 + (lane & 15);
        const int off = (ks * 64 + ((lane >> 4) << 4)) ^ ((lane & 7) << 4); // (row&7)==(lane&7)
        av[i] = *(const short8*)(lds + (arow << 7) + off);
        const int brow = wc * 64 + i * 16 + (lane & 15);
        bv[i] = *(const short8*)(lds + 16384 + (brow << 7) + off);
      }
#pragma unroll
      for (int i = 0; i < 4; ++i)
#pragma unroll
        for (int j = 0; j < 4; ++j)
          acc[i][j] = __builtin_amdgcn_mfma_f32_16x16x32_bf16(av[i], bv[j], acc[i][j], 0, 0, 0);
    }
    __syncthreads();
  }

  if (MODE == 0) {
#pragma unroll
    for (int j = 0; j < 4; ++j) {
      const int col = n0 + wc * 64 + j * 16 + (lane & 15);
      const int tsel = col >> 10;
      const int hd = col & 1023;
      const int hh = hd >> 6, d = hd & 63;
      const float bs = bias[col];
#pragma unroll
      for (int i = 0; i < 4; ++i) {
        const int rowb = m0 + wr * 64 + i * 16 + ((lane >> 4) << 2);
#pragma unroll
        for (int r = 0; r < 4; ++r) {
          const int row = rowb + r;
          const int b = row >> 11, kv = row & 2047;
          const int bh = b * NHEAD + hh;
          const u16 val = f2bf(acc[i][j][r] + bs);
          if (tsel == 0) {
            oq[((size_t)bh * SEQ + kv) * HDIM + d] = val;
          } else if (tsel == 1) {
            // K frag-major (5 chunks): tile 5120 u16; [kvblk(2)][ks(5)][lane(64)][j(8)]
            ok[((size_t)(bh * 32 + (kv >> 6))) * 5120 +
               (size_t)((kv >> 5) & 1) * 2560 +
               (size_t)(d >> 4) * 512 +
               (size_t)((((kv & 31) + (((d >> 3) & 1) << 5)) << 3) + (d & 7))] = val;
          } else {
            // V frag-major: [dblk(2)][s(4)][lane(64)][j(8)], tile 4096 u16
            ov[((size_t)(bh * 32 + (kv >> 6))) * 4096 +
               (size_t)((((d >> 5) << 2) + ((kv >> 4) & 3)) * 512) +
               (size_t)((((d & 31) + (((kv >> 3) & 1) << 5)) << 3) + (kv & 7))] = val;
          }
        }
      }
    }
  } else {
#pragma unroll
    for (int j = 0; j < 4; ++j) {
      const int col = n0 + wc * 64 + j * 16 + (lane & 15);
      const float bs = bias[col];
#pragma unroll
      for (int i = 0; i < 4; ++i) {
        const int rowb = m0 + wr * 64 + i * 16 + ((lane >> 4) << 2);
#pragma unroll
        for (int r = 0; r < 4; ++r)
          of[(size_t)(rowb + r) * MODELD + col] = acc[i][j][r] + bs;
      }
    }
  }
}

// ---------------- flash attention ----------------
// 32x32x16 MFMA, swapped operands; mask folded into K's 5th k-chunk (P=0 at masked
// positions straight out of exp2 -- no mask VALU/loads anywhere); P in-register via
// cvt_pk + permlane32_swap; frag-major K/V (linear lane*16 ds_reads, conflict-free).
// 1024 blocks x 128 threads (2 waves x 32 q-rows), dbuf LDS 36KB -> 4 blocks/CU.
__global__ __launch_bounds__(128) void flash_attn(const u16* __restrict__ q, const u16* __restrict__ kfr,
                                                  const u16* __restrict__ vfr,
                                                  u16* __restrict__ attnout) {
  // LDS: 2 x (K 10240 | V 8192) = 36864
  __shared__ __align__(16) char lds[36864];
  const int tid = threadIdx.x;
  const int lane = tid & 63, wid = tid >> 6;
  const int qi = lane & 31, h = lane >> 5;
  const int bid = blockIdx.x;
  const int xcd = bid & 7, rest = bid >> 3;           // 0..127
  const int bh = xcd * 4 + (rest >> 5);               // XCD-pinned: 4 heads per XCD
  const int q0 = (rest & 31) << 6;
  const int b = bh >> 4, hh = bh & 15;

  // Q B-frags: lane holds col=q, k = 16ks + 8h + j; 5th frag = constant e_64
  const int token = q0 + wid * 32 + qi;
  short8 qf[5];
  {
    const u16* qp = q + ((size_t)bh * SEQ + token) * HDIM;
#pragma unroll
    for (int ks = 0; ks < 4; ++ks) qf[ks] = *(const short8*)(qp + ks * 16 + h * 8);
    qf[4] = short8{};
    if (h == 0) qf[4][0] = (short)0x3F80;   // 1.0 at k=64
  }

  // staging: 9 x 16B per thread, fully linear
  const char* kg = (const char*)kfr + (size_t)bh * 32 * 10240;
  const char* vg = (const char*)vfr + (size_t)bh * 32 * 8192;
  const int so = tid << 4;
  auto stage = [&](int buf, int t) {
    char* dst = lds + buf * 18432;
    const char* ks = kg + (size_t)t * 10240;
    const char* vs = vg + (size_t)t * 8192;
#pragma unroll
    for (int i = 0; i < 5; ++i) gload_lds16(ks + i * 2048 + so, dst + i * 2048 + so);
#pragma unroll
    for (int i = 0; i < 4; ++i) gload_lds16(vs + i * 2048 + so, dst + 10240 + i * 2048 + so);
  };
  stage(0, 0);

  f32x16 o0 = {}, o1 = {};
  f32x4 ps = {0.f, 0.f, 0.f, 0.f};

  for (int t = 0; t < 32; ++t) {
    WAITVM(0);                                 // own stage(t) loads complete
    asm volatile("s_barrier" ::: "memory");    // both waves' stage(t) complete; compute(t-1) done
    if (t < 31) stage((t + 1) & 1, t + 1);     // prefetch overlaps compute(t)

    char* kb = lds + (t & 1) * 18432;
    char* vb = kb + 10240;

    // QK^T swapped + mask via 5th k-chunk: s[reg] = S[kv][q=qi] + (mask?0:-256)
    f32x16 s0 = {}, s1 = {};
    __builtin_amdgcn_s_setprio(1);
#pragma unroll
    for (int ks = 0; ks < 5; ++ks) {
      short8 ak0 = *(const short8*)(kb + (ks << 10) + (lane << 4));
      short8 ak1 = *(const short8*)(kb + 5120 + (ks << 10) + (lane << 4));
      s0 = __builtin_amdgcn_mfma_f32_32x32x16_bf16(ak0, qf[ks], s0, 0, 0, 0);
      s1 = __builtin_amdgcn_mfma_f32_32x32x16_bf16(ak1, qf[ks], s1, 0, 0, 0);
    }
    __builtin_amdgcn_s_setprio(0);

    // softmax: P = exp2(s) (masked entries underflow to exactly 0); psum in-register
    u32 w[16];
#pragma unroll
    for (int blk = 0; blk < 2; ++blk) {
#pragma unroll
      for (int g = 0; g < 4; ++g) {
        float e0, e1, e2, e3;
        if (blk == 0) {
          e0 = exp2f(s0[4 * g + 0]); e1 = exp2f(s0[4 * g + 1]);
          e2 = exp2f(s0[4 * g + 2]); e3 = exp2f(s0[4 * g + 3]);
        } else {
          e0 = exp2f(s1[4 * g + 0]); e1 = exp2f(s1[4 * g + 1]);
          e2 = exp2f(s1[4 * g + 2]); e3 = exp2f(s1[4 * g + 3]);
        }
        ps[0] += e0; ps[1] += e1; ps[2] += e2; ps[3] += e3;
        w[blk * 8 + 2 * g] = cvtpk(e0, e1);
        w[blk * 8 + 2 * g + 1] = cvtpk(e2, e3);
      }
    }
    // redistribute to PV B-frags (validated r8): frag s = (w[4s..4s+3])
    pl32(w[0], w[2]);  pl32(w[1], w[3]);
    pl32(w[4], w[6]);  pl32(w[5], w[7]);
    pl32(w[8], w[10]); pl32(w[9], w[11]);
    pl32(w[12], w[14]); pl32(w[13], w[15]);

    // PV swapped: O^T[d][q] += V . P
    __builtin_amdgcn_s_setprio(1);
#pragma unroll
    for (int s = 0; s < 4; ++s) {
      u32x4 pw = {w[4 * s], w[4 * s + 1], w[4 * s + 2], w[4 * s + 3]};
      short8 pf = __builtin_bit_cast(short8, pw);
      short8 av0 = *(const short8*)(vb + (s << 10) + (lane << 4));
      short8 av1 = *(const short8*)(vb + 4096 + (s << 10) + (lane << 4));
      o0 = __builtin_amdgcn_mfma_f32_32x32x16_bf16(av0, pf, o0, 0, 0, 0);
      o1 = __builtin_amdgcn_mfma_f32_32x32x16_bf16(av1, pf, o1, 0, 0, 0);
    }
    __builtin_amdgcn_s_setprio(0);
  }

  // lsum: own-h 32 kv rows + other h via one shuffle
  float l = (ps[0] + ps[1]) + (ps[2] + ps[3]);
  l += __shfl_xor(l, 32);
  const float inv = 1.0f / l;

  // O^T: lane owns column q=token; rows d = 32*dblk + 8g + 4h + {0..3}
  u16* outp = attnout + ((size_t)(b * SEQ + token)) * MODELD + hh * HDIM;
#pragma unroll
  for (int dblk = 0; dblk < 2; ++dblk) {
#pragma unroll
    for (int g = 0; g < 4; ++g) {
      float v0, v1, v2, v3;
      if (dblk == 0) {
        v0 = o0[4 * g + 0]; v1 = o0[4 * g + 1]; v2 = o0[4 * g + 2]; v3 = o0[4 * g + 3];
      } else {
        v0 = o1[4 * g + 0]; v1 = o1[4 * g + 1]; v2 = o1[4 * g + 2]; v3 = o1[4 * g + 3];
      }
      u32x2 ow;
      ow[0] = cvtpk(v0 * inv, v1 * inv);
      ow[1] = cvtpk(v2 * inv, v3 * inv);
      *(u32x2*)(outp + dblk * 32 + g * 8 + h * 4) = ow;
    }
  }
}

// ---------------- launch ----------------
extern "C" void kernel_launch(void* const* d_in, const int* in_sizes, int n_in,
                              void* d_out, int out_size, void* d_ws, size_t ws_size,
                              hipStream_t stream) {
  const float* x       = (const float*)d_in[0];
  const unsigned int* mask = (const unsigned int*)d_in[1];
  const float* w_qkv   = (const float*)d_in[2];
  const float* wq_base = (const float*)d_in[3];
  const float* bq      = (const float*)d_in[4];
  const float* wq_A    = (const float*)d_in[5];
  const float* wq_B    = (const float*)d_in[6];
  const float* wv_base = (const float*)d_in[7];
  const float* bv      = (const float*)d_in[8];
  const float* wv_A    = (const float*)d_in[9];
  const float* wv_B    = (const float*)d_in[10];
  const float* w_out   = (const float*)d_in[11];
  const float* b_out   = (const float*)d_in[12];
  float* out = (float*)d_out;

  char* ws = (char*)d_ws;
  u16* xb      = (u16*)(ws);                 // 8 MB  (reused as attnout)
  u16* wcomb   = (u16*)(ws + 8388608);       // 6 MB
  u16* woutb   = (u16*)(ws + 14680064);      // 2 MB
  u16* qws     = (u16*)(ws + 16777216);      // 8 MB  (row-major)
  u16* kws     = (u16*)(ws + 25165824);      // 10 MB (frag-major, 5 k-chunks)
  u16* vws     = (u16*)(ws + 35651584);      // 8 MB  (frag-major)
  float* biasc = (float*)(ws + 50331648);    // 12 KB
  u16* mbf     = (u16*)(ws + 50343936);      // 8 KB (bf16 1/0 mask)
  u16* attnout = xb;                          // xb dead after gemm_qkv

  prep_cast<<<4096, 256, 0, stream>>>(x, xb);          // 4M elems
  prep_cast<<<1024, 256, 0, stream>>>(w_out, woutb);   // 1M elems
  prep_mask<<<1, 1024, 0, stream>>>(mask, mbf);
  mask_ext<<<dim3(32, 32), 128, 0, stream>>>(mbf, kws);
  prep_w<<<3072, 256, 0, stream>>>(w_qkv, wq_base, bq, wq_A, wq_B,
                                   wv_base, bv, wv_A, wv_B, wcomb, biasc);

  gemm128<0><<<dim3(QKVCOLS / 128, MROWS / 128), 256, 0, stream>>>(
      xb, wcomb, biasc, qws, kws, vws, nullptr);

  flash_attn<<<1024, 128, 0, stream>>>(qws, kws, vws, attnout);

  gemm128<1><<<dim3(MODELD / 128, MROWS / 128), 256, 0, stream>>>(
      attnout, woutb, b_out, nullptr, nullptr, nullptr, out);
}

// Round 11
// 152.036 us; speedup vs baseline: 1.0897x; 1.0897x over previous
//
#include <hip/hip_runtime.h>

typedef unsigned short u16;
typedef unsigned int u32;
typedef __attribute__((ext_vector_type(2))) unsigned int u32x2;
typedef __attribute__((ext_vector_type(4))) unsigned int u32x4;
typedef __attribute__((ext_vector_type(4))) unsigned short u16x4;
typedef __attribute__((ext_vector_type(8))) unsigned short u16x8;
typedef __attribute__((ext_vector_type(8))) short short8;
typedef __attribute__((ext_vector_type(4))) float f32x4;
typedef __attribute__((ext_vector_type(16))) float f32x16;

#define NHEAD 16
#define HDIM 64
#define SEQ 2048
#define MODELD 1024
#define MROWS 4096            // B*N
#define QKVCOLS 3072
// ATT_SCALE * log2(e), folded into q weights/bias so softmax uses exp2
#define QSCALE 0.18033688011112042f

__device__ __forceinline__ u16 f2bf(float f) {
  union { float f; unsigned u; } v; v.f = f;
  unsigned r = v.u + 0x7FFFu + ((v.u >> 16) & 1u);
  return (u16)(r >> 16);
}

// packed f32x2 -> bf16x2 (RTNE), single instruction (T12)
__device__ __forceinline__ u32 cvtpk(float lo, float hi) {
  u32 r;
  asm("v_cvt_pk_bf16_f32 %0, %1, %2" : "=v"(r) : "v"(lo), "v"(hi));
  return r;
}

// v_permlane32_swap: a' = [a.lo32lanes | b.lo32lanes], b' = [a.hi | b.hi]
__device__ __forceinline__ void pl32(u32& a, u32& b) {
  asm("v_permlane32_swap_b32 %0, %1" : "+v"(a), "+v"(b));
}

__device__ __forceinline__ void gload_lds16(const void* g, void* l) {
  __builtin_amdgcn_global_load_lds((const __attribute__((address_space(1))) void*)g,
                                   (__attribute__((address_space(3))) void*)l, 16, 0, 0);
}

// ---------------- prep kernels ----------------

// f32 -> bf16, 4 elems/thread, exact grid
__global__ void prep_cast(const float* __restrict__ in, u16* __restrict__ outb) {
  int i = blockIdx.x * 256 + threadIdx.x;
  float4 v = *(const float4*)(in + (size_t)i * 4);
  u16x4 o = {f2bf(v.x), f2bf(v.y), f2bf(v.z), f2bf(v.w)};
  *(u16x4*)(outb + (size_t)i * 4) = o;
}

// mask -> bf16 K-ext value {keep: 0, masked: -256}; int32-vs-byte probe. 1x1024x4.
__global__ void prep_mask(const unsigned int* __restrict__ mraw, u16* __restrict__ mbf) {
  __shared__ int flag;
  const int tid = threadIdx.x;
  if (tid == 0) flag = 0;
  __syncthreads();
  if (mraw[tid] > 1u) flag = 1;   // race-benign
  __syncthreads();
  const int is_bytes = flag;
  const unsigned char* bp = (const unsigned char*)mraw;
  u16x4 o;
#pragma unroll
  for (int j = 0; j < 4; ++j) {
    unsigned v = is_bytes ? (unsigned)bp[tid * 4 + j] : mraw[tid * 4 + j];
    o[j] = v ? (u16)0 : (u16)0xC380;   // bf16 -256 when masked out
  }
  *(u16x4*)(mbf + tid * 4) = o;
}

// combined qkv weight (bf16) with LoRA + base fold; q rows pre-scaled by ATT_SCALE*log2e
__global__ void prep_w(const float* __restrict__ wqkv,
                       const float* __restrict__ wqb, const float* __restrict__ bq,
                       const float* __restrict__ wqA, const float* __restrict__ wqB,
                       const float* __restrict__ wvb, const float* __restrict__ bv,
                       const float* __restrict__ wvA, const float* __restrict__ wvB,
                       u16* __restrict__ wcomb, float* __restrict__ biasc) {
  const int c = blockIdx.x;             // 0..3071
  const int t = c >> 10, hd = c & 1023;
  const int k0 = threadIdx.x * 4;
  float4 w = *(const float4*)(wqkv + (size_t)c * MODELD + k0);
  float a0 = w.x, a1 = w.y, a2 = w.z, a3 = w.w;
  if (t != 1) {
    const float* base = (t == 0 ? wqb : wvb) + (size_t)hd * MODELD + k0;
    const float* A = (t == 0 ? wqA : wvA);
    const float* Bm = (t == 0 ? wqB : wvB) + hd * 10;
    float4 bsv = *(const float4*)base;
    a0 += bsv.x; a1 += bsv.y; a2 += bsv.z; a3 += bsv.w;
#pragma unroll
    for (int j = 0; j < 10; ++j) {
      float bj = Bm[j] * 0.1f;               // LORA_SCALE = 1/R
      float4 av = *(const float4*)(A + (size_t)j * MODELD + k0);
      a0 += bj * av.x; a1 += bj * av.y; a2 += bj * av.z; a3 += bj * av.w;
    }
    if (t == 0) { a0 *= QSCALE; a1 *= QSCALE; a2 *= QSCALE; a3 *= QSCALE; }
  }
  u16x4 o = {f2bf(a0), f2bf(a1), f2bf(a2), f2bf(a3)};
  *(u16x4*)(wcomb + (size_t)c * MODELD + k0) = o;
  if (threadIdx.x == 0)
    biasc[c] = (t == 0) ? QSCALE * bq[hd] : ((t == 2) ? bv[hd] : 0.f);
}

// ---------------- 128x128 bf16 MFMA GEMM, BK=64, swizzled LDS ----------------
// MODE 0: scatter q row-major, k/v FRAGMENT-MAJOR (4096 u16 per (bh,tile));
// MODE 1: f32 + bias
template<int MODE>
__global__ __launch_bounds__(256) void gemm128(const u16* __restrict__ A, const u16* __restrict__ W,
                                               const float* __restrict__ bias,
                                               u16* __restrict__ oq, u16* __restrict__ ok, u16* __restrict__ ov,
                                               float* __restrict__ of) {
  __shared__ __align__(16) char lds[32768];
  const int tid = threadIdx.x;
  const int lane = tid & 63;
  const int wid = tid >> 6;
  const int wr = wid >> 1, wc = wid & 1;
  const int m0 = blockIdx.y << 7;
  const int n0 = blockIdx.x << 7;
  const int K = MODELD;

  f32x4 acc[4][4] = {};

  const int so = wid * 1024 + (lane << 4);
  for (int kt = 0; kt < K; kt += 64) {
#pragma unroll
    for (int c = 0; c < 4; ++c) {
      const int o = c * 4096 + so;
      const int row = o >> 7;
      const int colb = (o & 127) ^ ((row & 7) << 4);   // inverse-swizzled global source (m173)
      gload_lds16((const char*)(A + (size_t)(m0 + row) * K + kt) + colb, lds + (c * 4096 + wid * 1024));
      gload_lds16((const char*)(W + (size_t)(n0 + row) * K + kt) + colb, lds + (16384 + c * 4096 + wid * 1024));
    }
    __syncthreads();
#pragma unroll
    for (int ks = 0; ks < 2; ++ks) {
      short8 av[4], bv[4];
#pragma unroll
      for (int i = 0; i < 4; ++i) {
        const int arow = wr * 64 + i * 16 + (lane & 15);
        const int off = (ks * 64 + ((lane >> 4) << 4)) ^ ((lane & 7) << 4); // (row&7)==(lane&7)
        av[i] = *(const short8*)(lds + (arow << 7) + off);
        const int brow = wc * 64 + i * 16 + (lane & 15);
        bv[i] = *(const short8*)(lds + 16384 + (brow << 7) + off);
      }
#pragma unroll
      for (int i = 0; i < 4; ++i)
#pragma unroll
        for (int j = 0; j < 4; ++j)
          acc[i][j] = __builtin_amdgcn_mfma_f32_16x16x32_bf16(av[i], bv[j], acc[i][j], 0, 0, 0);
    }
    __syncthreads();
  }

  if (MODE == 0) {
#pragma unroll
    for (int j = 0; j < 4; ++j) {
      const int col = n0 + wc * 64 + j * 16 + (lane & 15);
      const int tsel = col >> 10;
      const int hd = col & 1023;
      const int hh = hd >> 6, d = hd & 63;
      const float bs = bias[col];
#pragma unroll
      for (int i = 0; i < 4; ++i) {
        const int rowb = m0 + wr * 64 + i * 16 + ((lane >> 4) << 2);
#pragma unroll
        for (int r = 0; r < 4; ++r) {
          const int row = rowb + r;
          const int b = row >> 11, kv = row & 2047;
          const int bh = b * NHEAD + hh;
          const u16 val = f2bf(acc[i][j][r] + bs);
          if (tsel == 0) {
            oq[((size_t)bh * SEQ + kv) * HDIM + d] = val;
          } else if (tsel == 1) {
            // K frag-major: [kvblk(2)][ks(4)][lane(64)][j(8)], tile 4096 u16
            ok[((size_t)(bh * 32 + (kv >> 6))) * 4096 +
               (size_t)(((((kv >> 5) & 1) << 2) + (d >> 4)) * 512) +
               (size_t)((((kv & 31) + (((d >> 3) & 1) << 5)) << 3) + (d & 7))] = val;
          } else {
            // V frag-major: [dblk(2)][s(4)][lane(64)][j(8)], tile 4096 u16
            ov[((size_t)(bh * 32 + (kv >> 6))) * 4096 +
               (size_t)((((d >> 5) << 2) + ((kv >> 4) & 3)) * 512) +
               (size_t)((((d & 31) + (((kv >> 3) & 1) << 5)) << 3) + (kv & 7))] = val;
          }
        }
      }
    }
  } else {
#pragma unroll
    for (int j = 0; j < 4; ++j) {
      const int col = n0 + wc * 64 + j * 16 + (lane & 15);
      const float bs = bias[col];
#pragma unroll
      for (int i = 0; i < 4; ++i) {
        const int rowb = m0 + wr * 64 + i * 16 + ((lane >> 4) << 2);
#pragma unroll
        for (int r = 0; r < 4; ++r)
          of[(size_t)(rowb + r) * MODELD + col] = acc[i][j][r] + bs;
      }
    }
  }
}

// ---------------- flash attention (register-resident, no LDS, no barriers) ----------
// 2048 blocks x 64 threads (1 wave = 32 q rows). Frag-major K/V loaded DIRECTLY into
// VGPRs (each frag = base + lane*16, perfectly coalesced, L2-resident per XCD).
// Single-buffered with software pipelining: loadK(t+1) issued right after QK(t)
// consumes kS; loadV(t+1) after PV(t) -- each has a full compute phase to hide L2
// latency; compiler emits the counted vmcnt waits. Mask in the MFMA k-dim (k=64
// carries mask?0:-256, Q ext = e64), raw v_exp_f32 for exp2.
__global__ __launch_bounds__(64, 2) void flash_attn(const u16* __restrict__ q, const u16* __restrict__ kfr,
                                                    const u16* __restrict__ vfr, const u16* __restrict__ mbf,
                                                    u16* __restrict__ attnout) {
  const int lane = threadIdx.x;
  const int qi = lane & 31, h = lane >> 5;
  const int bid = blockIdx.x;
  const int xcd = bid & 7, rest = bid >> 3;           // 0..255
  const int bh = xcd * 4 + (rest >> 6);               // XCD-pinned: 4 heads per XCD
  const int q0 = (rest & 63) << 5;
  const int b = bh >> 4, hh = bh & 15;

  // Q B-frags: lane holds col=q=token, k = 16ks + 8h + j; ext frag = e_64
  const int token = q0 + qi;
  short8 qf[4], qf4 = {};
  {
    const u16* qp = q + ((size_t)bh * SEQ + token) * HDIM;
#pragma unroll
    for (int ks = 0; ks < 4; ++ks) qf[ks] = *(const short8*)(qp + ks * 16 + h * 8);
    if (h == 0) qf4[0] = (short)0x3F80;   // 1.0 at k=64
  }

  const u16* kg = kfr + (size_t)bh * 32 * 4096;
  const u16* vg = vfr + (size_t)bh * 32 * 4096;
  const u16* mrow = mbf + b * SEQ;
  const int lo = lane << 3;

  short8 kS[8], vS[8];
  u16 m0v, m1v;

  f32x16 o0 = {}, o1 = {};
  f32x4 ps = {0.f, 0.f, 0.f, 0.f};

  // prologue: tile 0
  {
    const u16* kt = kg;
    const u16* vt = vg;
#pragma unroll
    for (int i = 0; i < 8; ++i) kS[i] = *(const short8*)(kt + i * 512 + lo);
#pragma unroll
    for (int i = 0; i < 8; ++i) vS[i] = *(const short8*)(vt + i * 512 + lo);
    m0v = mrow[qi];
    m1v = mrow[32 + qi];
  }

  for (int t = 0; t < 32; ++t) {
    // mask ext A-frags (row kv, k=64 only: lanes<32, j=0)
    short8 e0 = {}, e1 = {};
    if (h == 0) { e0[0] = (short)m0v; e1[0] = (short)m1v; }

    // QK^T swapped: s[reg] = S[kv=(reg&3)+8(reg>>2)+4h+32blk][q=qi] + mask
    f32x16 s0 = {}, s1 = {};
    __builtin_amdgcn_s_setprio(1);
#pragma unroll
    for (int ks = 0; ks < 4; ++ks) {
      s0 = __builtin_amdgcn_mfma_f32_32x32x16_bf16(kS[ks], qf[ks], s0, 0, 0, 0);
      s1 = __builtin_amdgcn_mfma_f32_32x32x16_bf16(kS[4 + ks], qf[ks], s1, 0, 0, 0);
    }
    s0 = __builtin_amdgcn_mfma_f32_32x32x16_bf16(e0, qf4, s0, 0, 0, 0);
    s1 = __builtin_amdgcn_mfma_f32_32x32x16_bf16(e1, qf4, s1, 0, 0, 0);
    __builtin_amdgcn_s_setprio(0);

    // reload K + mask for t+1 (kS consumed; lands during SM+PV+next-QK-wait)
    if (t < 31) {
      const u16* kt = kg + (size_t)(t + 1) * 4096;
#pragma unroll
      for (int i = 0; i < 8; ++i) kS[i] = *(const short8*)(kt + i * 512 + lo);
      m0v = mrow[(t + 1) * 64 + qi];
      m1v = mrow[(t + 1) * 64 + 32 + qi];
    }

    // softmax: P = exp2(s) via raw v_exp_f32 (masked entries underflow to 0)
    u32 w[16];
#pragma unroll
    for (int blk = 0; blk < 2; ++blk) {
#pragma unroll
      for (int g = 0; g < 4; ++g) {
        float e0f, e1f, e2f, e3f;
        if (blk == 0) {
          e0f = __builtin_amdgcn_exp2f(s0[4 * g + 0]);
          e1f = __builtin_amdgcn_exp2f(s0[4 * g + 1]);
          e2f = __builtin_amdgcn_exp2f(s0[4 * g + 2]);
          e3f = __builtin_amdgcn_exp2f(s0[4 * g + 3]);
        } else {
          e0f = __builtin_amdgcn_exp2f(s1[4 * g + 0]);
          e1f = __builtin_amdgcn_exp2f(s1[4 * g + 1]);
          e2f = __builtin_amdgcn_exp2f(s1[4 * g + 2]);
          e3f = __builtin_amdgcn_exp2f(s1[4 * g + 3]);
        }
        ps[0] += e0f; ps[1] += e1f; ps[2] += e2f; ps[3] += e3f;
        w[blk * 8 + 2 * g] = cvtpk(e0f, e1f);
        w[blk * 8 + 2 * g + 1] = cvtpk(e2f, e3f);
      }
    }
    // redistribute to PV B-frags (validated r8/r10): frag s = (w[4s..4s+3])
    pl32(w[0], w[2]);  pl32(w[1], w[3]);
    pl32(w[4], w[6]);  pl32(w[5], w[7]);
    pl32(w[8], w[10]); pl32(w[9], w[11]);
    pl32(w[12], w[14]); pl32(w[13], w[15]);

    // PV swapped: O^T[d][q] += V . P
    __builtin_amdgcn_s_setprio(1);
#pragma unroll
    for (int s = 0; s < 4; ++s) {
      u32x4 pw = {w[4 * s], w[4 * s + 1], w[4 * s + 2], w[4 * s + 3]};
      short8 pf = __builtin_bit_cast(short8, pw);
      o0 = __builtin_amdgcn_mfma_f32_32x32x16_bf16(vS[s], pf, o0, 0, 0, 0);
      o1 = __builtin_amdgcn_mfma_f32_32x32x16_bf16(vS[4 + s], pf, o1, 0, 0, 0);
    }
    __builtin_amdgcn_s_setprio(0);

    // reload V for t+1 (vS consumed; lands during next tile's QK+SM)
    if (t < 31) {
      const u16* vt = vg + (size_t)(t + 1) * 4096;
#pragma unroll
      for (int i = 0; i < 8; ++i) vS[i] = *(const short8*)(vt + i * 512 + lo);
    }
  }

  // lsum: own-h 32 kv rows + other h via one shuffle
  float l = (ps[0] + ps[1]) + (ps[2] + ps[3]);
  l += __shfl_xor(l, 32);
  const float inv = 1.0f / l;

  // O^T: lane owns column q=token; rows d = 32*dblk + 8g + 4h + {0..3}
  u16* outp = attnout + ((size_t)(b * SEQ + token)) * MODELD + hh * HDIM;
#pragma unroll
  for (int dblk = 0; dblk < 2; ++dblk) {
#pragma unroll
    for (int g = 0; g < 4; ++g) {
      float v0, v1, v2, v3;
      if (dblk == 0) {
        v0 = o0[4 * g + 0]; v1 = o0[4 * g + 1]; v2 = o0[4 * g + 2]; v3 = o0[4 * g + 3];
      } else {
        v0 = o1[4 * g + 0]; v1 = o1[4 * g + 1]; v2 = o1[4 * g + 2]; v3 = o1[4 * g + 3];
      }
      u32x2 ow;
      ow[0] = cvtpk(v0 * inv, v1 * inv);
      ow[1] = cvtpk(v2 * inv, v3 * inv);
      *(u32x2*)(outp + dblk * 32 + g * 8 + h * 4) = ow;
    }
  }
}

// ---------------- launch ----------------
extern "C" void kernel_launch(void* const* d_in, const int* in_sizes, int n_in,
                              void* d_out, int out_size, void* d_ws, size_t ws_size,
                              hipStream_t stream) {
  const float* x       = (const float*)d_in[0];
  const unsigned int* mask = (const unsigned int*)d_in[1];
  const float* w_qkv   = (const float*)d_in[2];
  const float* wq_base = (const float*)d_in[3];
  const float* bq      = (const float*)d_in[4];
  const float* wq_A    = (const float*)d_in[5];
  const float* wq_B    = (const float*)d_in[6];
  const float* wv_base = (const float*)d_in[7];
  const float* bv      = (const float*)d_in[8];
  const float* wv_A    = (const float*)d_in[9];
  const float* wv_B    = (const float*)d_in[10];
  const float* w_out   = (const float*)d_in[11];
  const float* b_out   = (const float*)d_in[12];
  float* out = (float*)d_out;

  char* ws = (char*)d_ws;
  u16* xb      = (u16*)(ws);                 // 8 MB  (reused as attnout)
  u16* wcomb   = (u16*)(ws + 8388608);       // 6 MB
  u16* woutb   = (u16*)(ws + 14680064);      // 2 MB
  u16* qws     = (u16*)(ws + 16777216);      // 8 MB  (row-major)
  u16* kws     = (u16*)(ws + 25165824);      // 8 MB  (frag-major)
  u16* vws     = (u16*)(ws + 33554432);      // 8 MB  (frag-major)
  float* biasc = (float*)(ws + 50331648);    // 12 KB
  u16* mbf     = (u16*)(ws + 50343936);      // 8 KB (bf16 0 / -256 K-ext values)
  u16* attnout = xb;                          // xb dead after gemm_qkv

  prep_cast<<<4096, 256, 0, stream>>>(x, xb);          // 4M elems
  prep_cast<<<1024, 256, 0, stream>>>(w_out, woutb);   // 1M elems
  prep_mask<<<1, 1024, 0, stream>>>(mask, mbf);
  prep_w<<<3072, 256, 0, stream>>>(w_qkv, wq_base, bq, wq_A, wq_B,
                                   wv_base, bv, wv_A, wv_B, wcomb, biasc);

  gemm128<0><<<dim3(QKVCOLS / 128, MROWS / 128), 256, 0, stream>>>(
      xb, wcomb, biasc, qws, kws, vws, nullptr);

  flash_attn<<<2048, 64, 0, stream>>>(qws, kws, vws, mbf, attnout);

  gemm128<1><<<dim3(MODELD / 128, MROWS / 128), 256, 0, stream>>>(
      attnout, woutb, b_out, nullptr, nullptr, nullptr, out);
}

// Round 12
// 138.770 us; speedup vs baseline: 1.1939x; 1.0956x over previous
//
#include <hip/hip_runtime.h>

typedef unsigned short u16;
typedef unsigned int u32;
typedef __attribute__((ext_vector_type(2))) unsigned int u32x2;
typedef __attribute__((ext_vector_type(4))) unsigned int u32x4;
typedef __attribute__((ext_vector_type(4))) unsigned short u16x4;
typedef __attribute__((ext_vector_type(8))) unsigned short u16x8;
typedef __attribute__((ext_vector_type(8))) short short8;
typedef __attribute__((ext_vector_type(4))) float f32x4;
typedef __attribute__((ext_vector_type(16))) float f32x16;

#define NHEAD 16
#define HDIM 64
#define SEQ 2048
#define MODELD 1024
#define MROWS 4096            // B*N
#define QKVCOLS 3072
// ATT_SCALE * log2(e), folded into q weights/bias so softmax uses exp2
#define QSCALE 0.18033688011112042f

#define WAITVM(N) asm volatile("s_waitcnt vmcnt(" #N ")" ::: "memory")

__device__ __forceinline__ u16 f2bf(float f) {
  union { float f; unsigned u; } v; v.f = f;
  unsigned r = v.u + 0x7FFFu + ((v.u >> 16) & 1u);
  return (u16)(r >> 16);
}

// packed f32x2 -> bf16x2 (RTNE), single instruction (T12)
__device__ __forceinline__ u32 cvtpk(float lo, float hi) {
  u32 r;
  asm("v_cvt_pk_bf16_f32 %0, %1, %2" : "=v"(r) : "v"(lo), "v"(hi));
  return r;
}

// v_permlane32_swap: a' = [a.lo32lanes | b.lo32lanes], b' = [a.hi | b.hi]
__device__ __forceinline__ void pl32(u32& a, u32& b) {
  asm("v_permlane32_swap_b32 %0, %1" : "+v"(a), "+v"(b));
}

__device__ __forceinline__ void gload_lds16(const void* g, void* l) {
  __builtin_amdgcn_global_load_lds((const __attribute__((address_space(1))) void*)g,
                                   (__attribute__((address_space(3))) void*)l, 16, 0, 0);
}

// ---------------- prep kernels ----------------

// f32 -> bf16, 4 elems/thread, exact grid
__global__ void prep_cast(const float* __restrict__ in, u16* __restrict__ outb) {
  int i = blockIdx.x * 256 + threadIdx.x;
  float4 v = *(const float4*)(in + (size_t)i * 4);
  u16x4 o = {f2bf(v.x), f2bf(v.y), f2bf(v.z), f2bf(v.w)};
  *(u16x4*)(outb + (size_t)i * 4) = o;
}

// mask -> bf16 K-ext value {keep: 0, masked: -256}; int32-vs-byte probe. 1x1024x4.
__global__ void prep_mask(const unsigned int* __restrict__ mraw, u16* __restrict__ mbf) {
  __shared__ int flag;
  const int tid = threadIdx.x;
  if (tid == 0) flag = 0;
  __syncthreads();
  if (mraw[tid] > 1u) flag = 1;   // race-benign
  __syncthreads();
  const int is_bytes = flag;
  const unsigned char* bp = (const unsigned char*)mraw;
  u16x4 o;
#pragma unroll
  for (int j = 0; j < 4; ++j) {
    unsigned v = is_bytes ? (unsigned)bp[tid * 4 + j] : mraw[tid * 4 + j];
    o[j] = v ? (u16)0 : (u16)0xC380;   // bf16 -256 when masked out
  }
  *(u16x4*)(mbf + tid * 4) = o;
}

// combined qkv weight (bf16) with LoRA + base fold; q rows pre-scaled by ATT_SCALE*log2e
__global__ void prep_w(const float* __restrict__ wqkv,
                       const float* __restrict__ wqb, const float* __restrict__ bq,
                       const float* __restrict__ wqA, const float* __restrict__ wqB,
                       const float* __restrict__ wvb, const float* __restrict__ bv,
                       const float* __restrict__ wvA, const float* __restrict__ wvB,
                       u16* __restrict__ wcomb, float* __restrict__ biasc) {
  const int c = blockIdx.x;             // 0..3071
  const int t = c >> 10, hd = c & 1023;
  const int k0 = threadIdx.x * 4;
  float4 w = *(const float4*)(wqkv + (size_t)c * MODELD + k0);
  float a0 = w.x, a1 = w.y, a2 = w.z, a3 = w.w;
  if (t != 1) {
    const float* base = (t == 0 ? wqb : wvb) + (size_t)hd * MODELD + k0;
    const float* A = (t == 0 ? wqA : wvA);
    const float* Bm = (t == 0 ? wqB : wvB) + hd * 10;
    float4 bsv = *(const float4*)base;
    a0 += bsv.x; a1 += bsv.y; a2 += bsv.z; a3 += bsv.w;
#pragma unroll
    for (int j = 0; j < 10; ++j) {
      float bj = Bm[j] * 0.1f;               // LORA_SCALE = 1/R
      float4 av = *(const float4*)(A + (size_t)j * MODELD + k0);
      a0 += bj * av.x; a1 += bj * av.y; a2 += bj * av.z; a3 += bj * av.w;
    }
    if (t == 0) { a0 *= QSCALE; a1 *= QSCALE; a2 *= QSCALE; a3 *= QSCALE; }
  }
  u16x4 o = {f2bf(a0), f2bf(a1), f2bf(a2), f2bf(a3)};
  *(u16x4*)(wcomb + (size_t)c * MODELD + k0) = o;
  if (threadIdx.x == 0)
    biasc[c] = (t == 0) ? QSCALE * bq[hd] : ((t == 2) ? bv[hd] : 0.f);
}

// ---------------- 128x128 bf16 MFMA GEMM ----------------
// T3-min 2-phase: double-buffered LDS, stage(t+1) BEFORE compute(t), ONE barrier/step.
// XCD-aware chunk swizzle. MODE 0: LDS-imaged epilogue -> q row-major + k/v frag-major
// with fully coalesced 16B stores. MODE 1: f32 + bias direct.
template<int MODE>
__global__ __launch_bounds__(256) void gemm128(const u16* __restrict__ A, const u16* __restrict__ W,
                                               const float* __restrict__ bias,
                                               u16* __restrict__ oq, u16* __restrict__ ok, u16* __restrict__ ov,
                                               float* __restrict__ of) {
  __shared__ __align__(16) char lds[65536];     // 2 x (A 16K | B 16K)
  const int tid = threadIdx.x;
  const int lane = tid & 63;
  const int wid = tid >> 6;
  const int wr = wid >> 1, wc = wid & 1;
  const int nx = gridDim.x;
  int bid = blockIdx.y * nx + blockIdx.x;
  bid = (bid & 7) * ((nx * gridDim.y) >> 3) + (bid >> 3);   // XCD chunk (nwg%8==0)
  const int m0 = (bid / nx) << 7;
  const int n0 = (bid % nx) << 7;
  const int K = MODELD;

  f32x4 acc[4][4] = {};
  const int so = wid * 1024 + (lane << 4);

  auto stage = [&](int buf, int kt) {
    char* dst = lds + (buf << 15);
#pragma unroll
    for (int c = 0; c < 4; ++c) {
      const int o = c * 4096 + so;
      const int row = o >> 7;
      const int colb = (o & 127) ^ ((row & 7) << 4);   // inverse-swizzled global source (m173)
      gload_lds16((const char*)(A + (size_t)(m0 + row) * K + kt) + colb, dst + (c * 4096 + wid * 1024));
      gload_lds16((const char*)(W + (size_t)(n0 + row) * K + kt) + colb, dst + (16384 + c * 4096 + wid * 1024));
    }
  };

  stage(0, 0);
  __syncthreads();                    // vmcnt(0)+barrier: buf0 ready

  for (int t = 0; t < 16; ++t) {
    if (t < 15) stage((t + 1) & 1, (t + 1) << 6);   // overlaps compute(t)
    const char* base = lds + ((t & 1) << 15);
#pragma unroll
    for (int ks = 0; ks < 2; ++ks) {
      short8 av[4], bv[4];
#pragma unroll
      for (int i = 0; i < 4; ++i) {
        const int arow = wr * 64 + i * 16 + (lane & 15);
        const int off = (ks * 64 + ((lane >> 4) << 4)) ^ ((lane & 7) << 4); // (row&7)==(lane&7)
        av[i] = *(const short8*)(base + (arow << 7) + off);
        const int brow = wc * 64 + i * 16 + (lane & 15);
        bv[i] = *(const short8*)(base + 16384 + (brow << 7) + off);
      }
#pragma unroll
      for (int i = 0; i < 4; ++i)
#pragma unroll
        for (int j = 0; j < 4; ++j)
          acc[i][j] = __builtin_amdgcn_mfma_f32_16x16x32_bf16(av[i], bv[j], acc[i][j], 0, 0, 0);
    }
    __syncthreads();                  // drains stage(t+1) vmcnt + releases buf[t&1]
  }

  if (MODE == 0) {
    // build 32KB output image in LDS (16384 u16), then 8 coalesced 16B stores/thread
    u16* limg = (u16*)lds;
    const int tsel = n0 >> 10;        // block entirely within q/k/v region
    const int hd0 = n0 & 1023;
#pragma unroll
    for (int j = 0; j < 4; ++j) {
      const int cl = wc * 64 + j * 16 + (lane & 15);   // local col 0..127
      const int head = cl >> 6, d = cl & 63;
      const float bs = bias[n0 + cl];
#pragma unroll
      for (int i = 0; i < 4; ++i) {
        const int kvb = wr * 64 + i * 16 + ((lane >> 4) << 2);
#pragma unroll
        for (int r = 0; r < 4; ++r) {
          const int kvloc = kvb + r;                    // local row 0..127
          const u16 val = f2bf(acc[i][j][r] + bs);
          int off;
          if (tsel == 0) {
            off = head * 8192 + kvloc * 64 + d;
          } else if (tsel == 1) {
            const int kv = kvloc & 63;
            off = head * 8192 + (kvloc >> 6) * 4096 +
                  ((((kv >> 5) & 1) << 2) + (d >> 4)) * 512 +
                  (((kv & 31) + (((d >> 3) & 1) << 5)) << 3) + (d & 7);
          } else {
            const int kv = kvloc & 63;
            off = head * 8192 + (kvloc >> 6) * 4096 +
                  (((d >> 5) << 2) + ((kv >> 4) & 3)) * 512 +
                  (((d & 31) + (((kv >> 3) & 1) << 5)) << 3) + (kv & 7);
          }
          limg[off] = val;
        }
      }
    }
    __syncthreads();
    const int b = m0 >> 11;
#pragma unroll
    for (int p = 0; p < 8; ++p) {
      const int idx = p * 2048 + tid * 8;
      u16x8 v = *(const u16x8*)(limg + idx);
      const int headg = (hd0 >> 6) + (p >> 2);
      const size_t bh = (size_t)(b * NHEAD + headg);
      if (tsel == 0) {
        u16* dst = oq + (bh * SEQ + (m0 & 2047)) * HDIM + (p & 3) * 2048 + tid * 8;
        *(u16x8*)dst = v;
      } else {
        const int tileg = ((m0 & 2047) >> 6) + ((p >> 1) & 1);
        u16* basep = (tsel == 1) ? ok : ov;
        u16* dst = basep + (bh * 32 + tileg) * 4096 + (p & 1) * 2048 + tid * 8;
        *(u16x8*)dst = v;
      }
    }
  } else {
#pragma unroll
    for (int j = 0; j < 4; ++j) {
      const int col = n0 + wc * 64 + j * 16 + (lane & 15);
      const float bs = bias[col];
#pragma unroll
      for (int i = 0; i < 4; ++i) {
        const int rowb = m0 + wr * 64 + i * 16 + ((lane >> 4) << 2);
#pragma unroll
        for (int r = 0; r < 4; ++r)
          of[(size_t)(rowb + r) * MODELD + col] = acc[i][j][r] + bs;
      }
    }
  }
}

// ---------------- flash attention (register-resident, no LDS, no barriers) ----------
// 2048 blocks x 64 threads (1 wave = 32 q rows). Frag-major K/V loaded DIRECTLY into
// VGPRs (each frag = base + lane*16, perfectly coalesced, L2-resident per XCD).
// Single-buffered with software pipelining: loadK(t+1) issued right after QK(t)
// consumes kS; loadV(t+1) after PV(t) -- each has a full compute phase to hide L2
// latency; compiler emits the counted vmcnt waits. Mask in the MFMA k-dim (k=64
// carries mask?0:-256, Q ext = e64), raw v_exp_f32 for exp2.
__global__ __launch_bounds__(64, 2) void flash_attn(const u16* __restrict__ q, const u16* __restrict__ kfr,
                                                    const u16* __restrict__ vfr, const u16* __restrict__ mbf,
                                                    u16* __restrict__ attnout) {
  const int lane = threadIdx.x;
  const int qi = lane & 31, h = lane >> 5;
  const int bid = blockIdx.x;
  const int xcd = bid & 7, rest = bid >> 3;           // 0..255
  const int bh = xcd * 4 + (rest >> 6);               // XCD-pinned: 4 heads per XCD
  const int q0 = (rest & 63) << 5;
  const int b = bh >> 4, hh = bh & 15;

  // Q B-frags: lane holds col=q=token, k = 16ks + 8h + j; ext frag = e_64
  const int token = q0 + qi;
  short8 qf[4], qf4 = {};
  {
    const u16* qp = q + ((size_t)bh * SEQ + token) * HDIM;
#pragma unroll
    for (int ks = 0; ks < 4; ++ks) qf[ks] = *(const short8*)(qp + ks * 16 + h * 8);
    if (h == 0) qf4[0] = (short)0x3F80;   // 1.0 at k=64
  }

  const u16* kg = kfr + (size_t)bh * 32 * 4096;
  const u16* vg = vfr + (size_t)bh * 32 * 4096;
  const u16* mrow = mbf + b * SEQ;
  const int lo = lane << 3;

  short8 kS[8], vS[8];
  u16 m0v, m1v;

  f32x16 o0 = {}, o1 = {};
  f32x4 ps = {0.f, 0.f, 0.f, 0.f};

  // prologue: tile 0
  {
    const u16* kt = kg;
    const u16* vt = vg;
#pragma unroll
    for (int i = 0; i < 8; ++i) kS[i] = *(const short8*)(kt + i * 512 + lo);
#pragma unroll
    for (int i = 0; i < 8; ++i) vS[i] = *(const short8*)(vt + i * 512 + lo);
    m0v = mrow[qi];
    m1v = mrow[32 + qi];
  }

  for (int t = 0; t < 32; ++t) {
    // mask ext A-frags (row kv, k=64 only: lanes<32, j=0)
    short8 e0 = {}, e1 = {};
    if (h == 0) { e0[0] = (short)m0v; e1[0] = (short)m1v; }

    // QK^T swapped: s[reg] = S[kv=(reg&3)+8(reg>>2)+4h+32blk][q=qi] + mask
    f32x16 s0 = {}, s1 = {};
    __builtin_amdgcn_s_setprio(1);
#pragma unroll
    for (int ks = 0; ks < 4; ++ks) {
      s0 = __builtin_amdgcn_mfma_f32_32x32x16_bf16(kS[ks], qf[ks], s0, 0, 0, 0);
      s1 = __builtin_amdgcn_mfma_f32_32x32x16_bf16(kS[4 + ks], qf[ks], s1, 0, 0, 0);
    }
    s0 = __builtin_amdgcn_mfma_f32_32x32x16_bf16(e0, qf4, s0, 0, 0, 0);
    s1 = __builtin_amdgcn_mfma_f32_32x32x16_bf16(e1, qf4, s1, 0, 0, 0);
    __builtin_amdgcn_s_setprio(0);

    // reload K + mask for t+1 (kS consumed; lands during SM+PV+next-QK-wait)
    if (t < 31) {
      const u16* kt = kg + (size_t)(t + 1) * 4096;
#pragma unroll
      for (int i = 0; i < 8; ++i) kS[i] = *(const short8*)(kt + i * 512 + lo);
      m0v = mrow[(t + 1) * 64 + qi];
      m1v = mrow[(t + 1) * 64 + 32 + qi];
    }

    // softmax: P = exp2(s) via raw v_exp_f32 (masked entries underflow to 0)
    u32 w[16];
#pragma unroll
    for (int blk = 0; blk < 2; ++blk) {
#pragma unroll
      for (int g = 0; g < 4; ++g) {
        float e0f, e1f, e2f, e3f;
        if (blk == 0) {
          e0f = __builtin_amdgcn_exp2f(s0[4 * g + 0]);
          e1f = __builtin_amdgcn_exp2f(s0[4 * g + 1]);
          e2f = __builtin_amdgcn_exp2f(s0[4 * g + 2]);
          e3f = __builtin_amdgcn_exp2f(s0[4 * g + 3]);
        } else {
          e0f = __builtin_amdgcn_exp2f(s1[4 * g + 0]);
          e1f = __builtin_amdgcn_exp2f(s1[4 * g + 1]);
          e2f = __builtin_amdgcn_exp2f(s1[4 * g + 2]);
          e3f = __builtin_amdgcn_exp2f(s1[4 * g + 3]);
        }
        ps[0] += e0f; ps[1] += e1f; ps[2] += e2f; ps[3] += e3f;
        w[blk * 8 + 2 * g] = cvtpk(e0f, e1f);
        w[blk * 8 + 2 * g + 1] = cvtpk(e2f, e3f);
      }
    }
    // redistribute to PV B-frags (validated r8/r10/r11): frag s = (w[4s..4s+3])
    pl32(w[0], w[2]);  pl32(w[1], w[3]);
    pl32(w[4], w[6]);  pl32(w[5], w[7]);
    pl32(w[8], w[10]); pl32(w[9], w[11]);
    pl32(w[12], w[14]); pl32(w[13], w[15]);

    // PV swapped: O^T[d][q] += V . P
    __builtin_amdgcn_s_setprio(1);
#pragma unroll
    for (int s = 0; s < 4; ++s) {
      u32x4 pw = {w[4 * s], w[4 * s + 1], w[4 * s + 2], w[4 * s + 3]};
      short8 pf = __builtin_bit_cast(short8, pw);
      o0 = __builtin_amdgcn_mfma_f32_32x32x16_bf16(vS[s], pf, o0, 0, 0, 0);
      o1 = __builtin_amdgcn_mfma_f32_32x32x16_bf16(vS[4 + s], pf, o1, 0, 0, 0);
    }
    __builtin_amdgcn_s_setprio(0);

    // reload V for t+1 (vS consumed; lands during next tile's QK+SM)
    if (t < 31) {
      const u16* vt = vg + (size_t)(t + 1) * 4096;
#pragma unroll
      for (int i = 0; i < 8; ++i) vS[i] = *(const short8*)(vt + i * 512 + lo);
    }
  }

  // lsum: own-h 32 kv rows + other h via one shuffle
  float l = (ps[0] + ps[1]) + (ps[2] + ps[3]);
  l += __shfl_xor(l, 32);
  const float inv = 1.0f / l;

  // O^T: lane owns column q=token; rows d = 32*dblk + 8g + 4h + {0..3}
  u16* outp = attnout + ((size_t)(b * SEQ + token)) * MODELD + hh * HDIM;
#pragma unroll
  for (int dblk = 0; dblk < 2; ++dblk) {
#pragma unroll
    for (int g = 0; g < 4; ++g) {
      float v0, v1, v2, v3;
      if (dblk == 0) {
        v0 = o0[4 * g + 0]; v1 = o0[4 * g + 1]; v2 = o0[4 * g + 2]; v3 = o0[4 * g + 3];
      } else {
        v0 = o1[4 * g + 0]; v1 = o1[4 * g + 1]; v2 = o1[4 * g + 2]; v3 = o1[4 * g + 3];
      }
      u32x2 ow;
      ow[0] = cvtpk(v0 * inv, v1 * inv);
      ow[1] = cvtpk(v2 * inv, v3 * inv);
      *(u32x2*)(outp + dblk * 32 + g * 8 + h * 4) = ow;
    }
  }
}

// ---------------- launch ----------------
extern "C" void kernel_launch(void* const* d_in, const int* in_sizes, int n_in,
                              void* d_out, int out_size, void* d_ws, size_t ws_size,
                              hipStream_t stream) {
  const float* x       = (const float*)d_in[0];
  const unsigned int* mask = (const unsigned int*)d_in[1];
  const float* w_qkv   = (const float*)d_in[2];
  const float* wq_base = (const float*)d_in[3];
  const float* bq      = (const float*)d_in[4];
  const float* wq_A    = (const float*)d_in[5];
  const float* wq_B    = (const float*)d_in[6];
  const float* wv_base = (const float*)d_in[7];
  const float* bv      = (const float*)d_in[8];
  const float* wv_A    = (const float*)d_in[9];
  const float* wv_B    = (const float*)d_in[10];
  const float* w_out   = (const float*)d_in[11];
  const float* b_out   = (const float*)d_in[12];
  float* out = (float*)d_out;

  char* ws = (char*)d_ws;
  u16* xb      = (u16*)(ws);                 // 8 MB  (reused as attnout)
  u16* wcomb   = (u16*)(ws + 8388608);       // 6 MB
  u16* woutb   = (u16*)(ws + 14680064);      // 2 MB
  u16* qws     = (u16*)(ws + 16777216);      // 8 MB  (row-major)
  u16* kws     = (u16*)(ws + 25165824);      // 8 MB  (frag-major)
  u16* vws     = (u16*)(ws + 33554432);      // 8 MB  (frag-major)
  float* biasc = (float*)(ws + 50331648);    // 12 KB
  u16* mbf     = (u16*)(ws + 50343936);      // 8 KB (bf16 0 / -256 K-ext values)
  u16* attnout = xb;                          // xb dead after gemm_qkv

  prep_cast<<<4096, 256, 0, stream>>>(x, xb);          // 4M elems
  prep_cast<<<1024, 256, 0, stream>>>(w_out, woutb);   // 1M elems
  prep_mask<<<1, 1024, 0, stream>>>(mask, mbf);
  prep_w<<<3072, 256, 0, stream>>>(w_qkv, wq_base, bq, wq_A, wq_B,
                                   wv_base, bv, wv_A, wv_B, wcomb, biasc);

  gemm128<0><<<dim3(QKVCOLS / 128, MROWS / 128), 256, 0, stream>>>(
      xb, wcomb, biasc, qws, kws, vws, nullptr);

  flash_attn<<<2048, 64, 0, stream>>>(qws, kws, vws, mbf, attnout);

  gemm128<1><<<dim3(MODELD / 128, MROWS / 128), 256, 0, stream>>>(
      attnout, woutb, b_out, nullptr, nullptr, nullptr, out);
}

// Round 13
// 137.686 us; speedup vs baseline: 1.2033x; 1.0079x over previous
//
#include <hip/hip_runtime.h>

typedef unsigned short u16;
typedef unsigned int u32;
typedef __attribute__((ext_vector_type(2))) unsigned int u32x2;
typedef __attribute__((ext_vector_type(4))) unsigned int u32x4;
typedef __attribute__((ext_vector_type(4))) unsigned short u16x4;
typedef __attribute__((ext_vector_type(8))) unsigned short u16x8;
typedef __attribute__((ext_vector_type(8))) short short8;
typedef __attribute__((ext_vector_type(4))) float f32x4;
typedef __attribute__((ext_vector_type(16))) float f32x16;

#define NHEAD 16
#define HDIM 64
#define SEQ 2048
#define MODELD 1024
#define MROWS 4096            // B*N
#define QKVCOLS 3072
// ATT_SCALE * log2(e), folded into q weights/bias so softmax uses exp2
#define QSCALE 0.18033688011112042f

__device__ __forceinline__ u16 f2bf(float f) {
  union { float f; unsigned u; } v; v.f = f;
  unsigned r = v.u + 0x7FFFu + ((v.u >> 16) & 1u);
  return (u16)(r >> 16);
}

// packed f32x2 -> bf16x2 (RTNE), single instruction (T12)
__device__ __forceinline__ u32 cvtpk(float lo, float hi) {
  u32 r;
  asm("v_cvt_pk_bf16_f32 %0, %1, %2" : "=v"(r) : "v"(lo), "v"(hi));
  return r;
}

// v_permlane32_swap: a' = [a.lo32lanes | b.lo32lanes], b' = [a.hi | b.hi]
__device__ __forceinline__ void pl32(u32& a, u32& b) {
  asm("v_permlane32_swap_b32 %0, %1" : "+v"(a), "+v"(b));
}

__device__ __forceinline__ void gload_lds16(const void* g, void* l) {
  __builtin_amdgcn_global_load_lds((const __attribute__((address_space(1))) void*)g,
                                   (__attribute__((address_space(3))) void*)l, 16, 0, 0);
}

// ---------------- prep kernels ----------------

// f32 -> bf16, 4 elems/thread, exact grid
__global__ void prep_cast(const float* __restrict__ in, u16* __restrict__ outb) {
  int i = blockIdx.x * 256 + threadIdx.x;
  float4 v = *(const float4*)(in + (size_t)i * 4);
  u16x4 o = {f2bf(v.x), f2bf(v.y), f2bf(v.z), f2bf(v.w)};
  *(u16x4*)(outb + (size_t)i * 4) = o;
}

// mask -> bf16 K-ext value {keep: 0, masked: -256}; int32-vs-byte probe. 1x1024x4.
__global__ void prep_mask(const unsigned int* __restrict__ mraw, u16* __restrict__ mbf) {
  __shared__ int flag;
  const int tid = threadIdx.x;
  if (tid == 0) flag = 0;
  __syncthreads();
  if (mraw[tid] > 1u) flag = 1;   // race-benign
  __syncthreads();
  const int is_bytes = flag;
  const unsigned char* bp = (const unsigned char*)mraw;
  u16x4 o;
#pragma unroll
  for (int j = 0; j < 4; ++j) {
    unsigned v = is_bytes ? (unsigned)bp[tid * 4 + j] : mraw[tid * 4 + j];
    o[j] = v ? (u16)0 : (u16)0xC380;   // bf16 -256 when masked out
  }
  *(u16x4*)(mbf + tid * 4) = o;
}

// combined qkv weight (bf16) with LoRA + base fold; q rows pre-scaled by ATT_SCALE*log2e
__global__ void prep_w(const float* __restrict__ wqkv,
                       const float* __restrict__ wqb, const float* __restrict__ bq,
                       const float* __restrict__ wqA, const float* __restrict__ wqB,
                       const float* __restrict__ wvb, const float* __restrict__ bv,
                       const float* __restrict__ wvA, const float* __restrict__ wvB,
                       u16* __restrict__ wcomb, float* __restrict__ biasc) {
  const int c = blockIdx.x;             // 0..3071
  const int t = c >> 10, hd = c & 1023;
  const int k0 = threadIdx.x * 4;
  float4 w = *(const float4*)(wqkv + (size_t)c * MODELD + k0);
  float a0 = w.x, a1 = w.y, a2 = w.z, a3 = w.w;
  if (t != 1) {
    const float* base = (t == 0 ? wqb : wvb) + (size_t)hd * MODELD + k0;
    const float* A = (t == 0 ? wqA : wvA);
    const float* Bm = (t == 0 ? wqB : wvB) + hd * 10;
    float4 bsv = *(const float4*)base;
    a0 += bsv.x; a1 += bsv.y; a2 += bsv.z; a3 += bsv.w;
#pragma unroll
    for (int j = 0; j < 10; ++j) {
      float bj = Bm[j] * 0.1f;               // LORA_SCALE = 1/R
      float4 av = *(const float4*)(A + (size_t)j * MODELD + k0);
      a0 += bj * av.x; a1 += bj * av.y; a2 += bj * av.z; a3 += bj * av.w;
    }
    if (t == 0) { a0 *= QSCALE; a1 *= QSCALE; a2 *= QSCALE; a3 *= QSCALE; }
  }
  u16x4 o = {f2bf(a0), f2bf(a1), f2bf(a2), f2bf(a3)};
  *(u16x4*)(wcomb + (size_t)c * MODELD + k0) = o;
  if (threadIdx.x == 0)
    biasc[c] = (t == 0) ? QSCALE * bq[hd] : ((t == 2) ? bv[hd] : 0.f);
}

// ---------------- 128x128 bf16 MFMA GEMM ----------------
// T3-min 2-phase: double-buffered LDS, stage(t+1) BEFORE compute(t), ONE barrier/step.
// XCD-aware chunk swizzle. MODE 0: LDS-imaged epilogue -> q row-major + k/v frag-major
// with fully coalesced 16B stores. MODE 1: f32 + bias direct.
template<int MODE>
__global__ __launch_bounds__(256) void gemm128(const u16* __restrict__ A, const u16* __restrict__ W,
                                               const float* __restrict__ bias,
                                               u16* __restrict__ oq, u16* __restrict__ ok, u16* __restrict__ ov,
                                               float* __restrict__ of) {
  __shared__ __align__(16) char lds[65536];     // 2 x (A 16K | B 16K)
  const int tid = threadIdx.x;
  const int lane = tid & 63;
  const int wid = tid >> 6;
  const int wr = wid >> 1, wc = wid & 1;
  const int nx = gridDim.x;
  int bid = blockIdx.y * nx + blockIdx.x;
  bid = (bid & 7) * ((nx * gridDim.y) >> 3) + (bid >> 3);   // XCD chunk (nwg%8==0)
  const int m0 = (bid / nx) << 7;
  const int n0 = (bid % nx) << 7;
  const int K = MODELD;

  f32x4 acc[4][4] = {};
  const int so = wid * 1024 + (lane << 4);

  auto stage = [&](int buf, int kt) {
    char* dst = lds + (buf << 15);
#pragma unroll
    for (int c = 0; c < 4; ++c) {
      const int o = c * 4096 + so;
      const int row = o >> 7;
      const int colb = (o & 127) ^ ((row & 7) << 4);   // inverse-swizzled global source (m173)
      gload_lds16((const char*)(A + (size_t)(m0 + row) * K + kt) + colb, dst + (c * 4096 + wid * 1024));
      gload_lds16((const char*)(W + (size_t)(n0 + row) * K + kt) + colb, dst + (16384 + c * 4096 + wid * 1024));
    }
  };

  stage(0, 0);
  __syncthreads();                    // vmcnt(0)+barrier: buf0 ready

  for (int t = 0; t < 16; ++t) {
    if (t < 15) stage((t + 1) & 1, (t + 1) << 6);   // overlaps compute(t)
    const char* base = lds + ((t & 1) << 15);
#pragma unroll
    for (int ks = 0; ks < 2; ++ks) {
      short8 av[4], bv[4];
#pragma unroll
      for (int i = 0; i < 4; ++i) {
        const int arow = wr * 64 + i * 16 + (lane & 15);
        const int off = (ks * 64 + ((lane >> 4) << 4)) ^ ((lane & 7) << 4); // (row&7)==(lane&7)
        av[i] = *(const short8*)(base + (arow << 7) + off);
        const int brow = wc * 64 + i * 16 + (lane & 15);
        bv[i] = *(const short8*)(base + 16384 + (brow << 7) + off);
      }
#pragma unroll
      for (int i = 0; i < 4; ++i)
#pragma unroll
        for (int j = 0; j < 4; ++j)
          acc[i][j] = __builtin_amdgcn_mfma_f32_16x16x32_bf16(av[i], bv[j], acc[i][j], 0, 0, 0);
    }
    __syncthreads();                  // drains stage(t+1) vmcnt + releases buf[t&1]
  }

  if (MODE == 0) {
    // build 32KB output image in LDS (16384 u16), then 8 coalesced 16B stores/thread
    u16* limg = (u16*)lds;
    const int tsel = n0 >> 10;        // block entirely within q/k/v region
    const int hd0 = n0 & 1023;
#pragma unroll
    for (int j = 0; j < 4; ++j) {
      const int cl = wc * 64 + j * 16 + (lane & 15);   // local col 0..127
      const int head = cl >> 6, d = cl & 63;
      const float bs = bias[n0 + cl];
#pragma unroll
      for (int i = 0; i < 4; ++i) {
        const int kvb = wr * 64 + i * 16 + ((lane >> 4) << 2);
#pragma unroll
        for (int r = 0; r < 4; ++r) {
          const int kvloc = kvb + r;                    // local row 0..127
          const u16 val = f2bf(acc[i][j][r] + bs);
          int off;
          if (tsel == 0) {
            off = head * 8192 + kvloc * 64 + d;
          } else if (tsel == 1) {
            const int kv = kvloc & 63;
            off = head * 8192 + (kvloc >> 6) * 4096 +
                  ((((kv >> 5) & 1) << 2) + (d >> 4)) * 512 +
                  (((kv & 31) + (((d >> 3) & 1) << 5)) << 3) + (d & 7);
          } else {
            const int kv = kvloc & 63;
            off = head * 8192 + (kvloc >> 6) * 4096 +
                  (((d >> 5) << 2) + ((kv >> 4) & 3)) * 512 +
                  (((d & 31) + (((kv >> 3) & 1) << 5)) << 3) + (kv & 7);
          }
          limg[off] = val;
        }
      }
    }
    __syncthreads();
    const int b = m0 >> 11;
#pragma unroll
    for (int p = 0; p < 8; ++p) {
      const int idx = p * 2048 + tid * 8;
      u16x8 v = *(const u16x8*)(limg + idx);
      const int headg = (hd0 >> 6) + (p >> 2);
      const size_t bh = (size_t)(b * NHEAD + headg);
      if (tsel == 0) {
        u16* dst = oq + (bh * SEQ + (m0 & 2047)) * HDIM + (p & 3) * 2048 + tid * 8;
        *(u16x8*)dst = v;
      } else {
        const int tileg = ((m0 & 2047) >> 6) + ((p >> 1) & 1);
        u16* basep = (tsel == 1) ? ok : ov;
        u16* dst = basep + (bh * 32 + tileg) * 4096 + (p & 1) * 2048 + tid * 8;
        *(u16x8*)dst = v;
      }
    }
  } else {
#pragma unroll
    for (int j = 0; j < 4; ++j) {
      const int col = n0 + wc * 64 + j * 16 + (lane & 15);
      const float bs = bias[col];
#pragma unroll
      for (int i = 0; i < 4; ++i) {
        const int rowb = m0 + wr * 64 + i * 16 + ((lane >> 4) << 2);
#pragma unroll
        for (int r = 0; r < 4; ++r)
          of[(size_t)(rowb + r) * MODELD + col] = acc[i][j][r] + bs;
      }
    }
  }
}

// ---------------- flash attention (register-resident, 64 q-rows/wave) ----------
// 1024 blocks x 64 threads. Each wave owns TWO 32-q sub-problems (A at q0, B at
// q0+32) sharing every K/V register load -> L2 traffic halved vs r12 (floor 16us).
// ILP replaces TLP: while SM-A runs on the VALU, QK-B feeds the MFMA pipe.
// Schedule/tile: QK-A, SM-A, PV-A, QK-B, loadK(t+1), SM-B, PV-B, loadV(t+1) --
// ~250-500cy use-distance on each load burst. Mask in the MFMA k-dim, raw v_exp_f32.
__global__ __launch_bounds__(64) void flash_attn(const u16* __restrict__ q, const u16* __restrict__ kfr,
                                                 const u16* __restrict__ vfr, const u16* __restrict__ mbf,
                                                 u16* __restrict__ attnout) {
  const int lane = threadIdx.x;
  const int qi = lane & 31, h = lane >> 5;
  const int bid = blockIdx.x;
  const int xcd = bid & 7, rest = bid >> 3;           // 0..127
  const int bh = xcd * 4 + (rest >> 5);               // XCD-pinned: 4 heads per XCD
  const int q0 = (rest & 31) << 6;
  const int b = bh >> 4, hh = bh & 15;

  // Q B-frags for both sub-problems: lane holds col=q, k = 16ks + 8h + j
  const int tokenA = q0 + qi;
  short8 qfA[4], qfB[4], qf4 = {};
  {
    const u16* qp = q + ((size_t)bh * SEQ + tokenA) * HDIM;
#pragma unroll
    for (int ks = 0; ks < 4; ++ks) {
      qfA[ks] = *(const short8*)(qp + ks * 16 + h * 8);
      qfB[ks] = *(const short8*)(qp + 32 * HDIM + ks * 16 + h * 8);
    }
    if (h == 0) qf4[0] = (short)0x3F80;   // 1.0 at k=64
  }

  const u16* kg = kfr + (size_t)bh * 32 * 4096;
  const u16* vg = vfr + (size_t)bh * 32 * 4096;
  const u16* mrow = mbf + b * SEQ;
  const int lo = lane << 3;

  short8 kS[8], vS[8];
  u16 m0v, m1v;

  f32x16 oA0 = {}, oA1 = {}, oB0 = {}, oB1 = {};
  f32x4 psA = {0.f, 0.f, 0.f, 0.f}, psB = {0.f, 0.f, 0.f, 0.f};

  // prologue: tile 0
  {
#pragma unroll
    for (int i = 0; i < 8; ++i) kS[i] = *(const short8*)(kg + i * 512 + lo);
#pragma unroll
    for (int i = 0; i < 8; ++i) vS[i] = *(const short8*)(vg + i * 512 + lo);
    m0v = mrow[qi];
    m1v = mrow[32 + qi];
  }

  for (int t = 0; t < 32; ++t) {
    // mask ext A-frags (row kv, k=64 only: lanes<32, j=0) -- shared by A and B
    short8 e0 = {}, e1 = {};
    if (h == 0) { e0[0] = (short)m0v; e1[0] = (short)m1v; }

    // ---- QK-A ----
    f32x16 s0 = {}, s1 = {};
    __builtin_amdgcn_s_setprio(1);
#pragma unroll
    for (int ks = 0; ks < 4; ++ks) {
      s0 = __builtin_amdgcn_mfma_f32_32x32x16_bf16(kS[ks], qfA[ks], s0, 0, 0, 0);
      s1 = __builtin_amdgcn_mfma_f32_32x32x16_bf16(kS[4 + ks], qfA[ks], s1, 0, 0, 0);
    }
    s0 = __builtin_amdgcn_mfma_f32_32x32x16_bf16(e0, qf4, s0, 0, 0, 0);
    s1 = __builtin_amdgcn_mfma_f32_32x32x16_bf16(e1, qf4, s1, 0, 0, 0);
    __builtin_amdgcn_s_setprio(0);

    // ---- SM-A ----
    u32 w[16];
#pragma unroll
    for (int blk = 0; blk < 2; ++blk) {
#pragma unroll
      for (int g = 0; g < 4; ++g) {
        float e0f, e1f, e2f, e3f;
        if (blk == 0) {
          e0f = __builtin_amdgcn_exp2f(s0[4 * g + 0]);
          e1f = __builtin_amdgcn_exp2f(s0[4 * g + 1]);
          e2f = __builtin_amdgcn_exp2f(s0[4 * g + 2]);
          e3f = __builtin_amdgcn_exp2f(s0[4 * g + 3]);
        } else {
          e0f = __builtin_amdgcn_exp2f(s1[4 * g + 0]);
          e1f = __builtin_amdgcn_exp2f(s1[4 * g + 1]);
          e2f = __builtin_amdgcn_exp2f(s1[4 * g + 2]);
          e3f = __builtin_amdgcn_exp2f(s1[4 * g + 3]);
        }
        psA[0] += e0f; psA[1] += e1f; psA[2] += e2f; psA[3] += e3f;
        w[blk * 8 + 2 * g] = cvtpk(e0f, e1f);
        w[blk * 8 + 2 * g + 1] = cvtpk(e2f, e3f);
      }
    }
    pl32(w[0], w[2]);  pl32(w[1], w[3]);
    pl32(w[4], w[6]);  pl32(w[5], w[7]);
    pl32(w[8], w[10]); pl32(w[9], w[11]);
    pl32(w[12], w[14]); pl32(w[13], w[15]);

    // ---- PV-A ----
    __builtin_amdgcn_s_setprio(1);
#pragma unroll
    for (int s = 0; s < 4; ++s) {
      u32x4 pw = {w[4 * s], w[4 * s + 1], w[4 * s + 2], w[4 * s + 3]};
      short8 pf = __builtin_bit_cast(short8, pw);
      oA0 = __builtin_amdgcn_mfma_f32_32x32x16_bf16(vS[s], pf, oA0, 0, 0, 0);
      oA1 = __builtin_amdgcn_mfma_f32_32x32x16_bf16(vS[4 + s], pf, oA1, 0, 0, 0);
    }

    // ---- QK-B (kS last use) ----
    f32x16 r0 = {}, r1 = {};
#pragma unroll
    for (int ks = 0; ks < 4; ++ks) {
      r0 = __builtin_amdgcn_mfma_f32_32x32x16_bf16(kS[ks], qfB[ks], r0, 0, 0, 0);
      r1 = __builtin_amdgcn_mfma_f32_32x32x16_bf16(kS[4 + ks], qfB[ks], r1, 0, 0, 0);
    }
    r0 = __builtin_amdgcn_mfma_f32_32x32x16_bf16(e0, qf4, r0, 0, 0, 0);
    r1 = __builtin_amdgcn_mfma_f32_32x32x16_bf16(e1, qf4, r1, 0, 0, 0);
    __builtin_amdgcn_s_setprio(0);

    // reload K + mask for t+1 (use at QK-A(t+1): gap = SM-B + PV-B)
    if (t < 31) {
      const u16* kt = kg + (size_t)(t + 1) * 4096;
#pragma unroll
      for (int i = 0; i < 8; ++i) kS[i] = *(const short8*)(kt + i * 512 + lo);
      m0v = mrow[(t + 1) * 64 + qi];
      m1v = mrow[(t + 1) * 64 + 32 + qi];
    }

    // ---- SM-B ----
#pragma unroll
    for (int blk = 0; blk < 2; ++blk) {
#pragma unroll
      for (int g = 0; g < 4; ++g) {
        float e0f, e1f, e2f, e3f;
        if (blk == 0) {
          e0f = __builtin_amdgcn_exp2f(r0[4 * g + 0]);
          e1f = __builtin_amdgcn_exp2f(r0[4 * g + 1]);
          e2f = __builtin_amdgcn_exp2f(r0[4 * g + 2]);
          e3f = __builtin_amdgcn_exp2f(r0[4 * g + 3]);
        } else {
          e0f = __builtin_amdgcn_exp2f(r1[4 * g + 0]);
          e1f = __builtin_amdgcn_exp2f(r1[4 * g + 1]);
          e2f = __builtin_amdgcn_exp2f(r1[4 * g + 2]);
          e3f = __builtin_amdgcn_exp2f(r1[4 * g + 3]);
        }
        psB[0] += e0f; psB[1] += e1f; psB[2] += e2f; psB[3] += e3f;
        w[blk * 8 + 2 * g] = cvtpk(e0f, e1f);
        w[blk * 8 + 2 * g + 1] = cvtpk(e2f, e3f);
      }
    }
    pl32(w[0], w[2]);  pl32(w[1], w[3]);
    pl32(w[4], w[6]);  pl32(w[5], w[7]);
    pl32(w[8], w[10]); pl32(w[9], w[11]);
    pl32(w[12], w[14]); pl32(w[13], w[15]);

    // ---- PV-B (vS last use) ----
    __builtin_amdgcn_s_setprio(1);
#pragma unroll
    for (int s = 0; s < 4; ++s) {
      u32x4 pw = {w[4 * s], w[4 * s + 1], w[4 * s + 2], w[4 * s + 3]};
      short8 pf = __builtin_bit_cast(short8, pw);
      oB0 = __builtin_amdgcn_mfma_f32_32x32x16_bf16(vS[s], pf, oB0, 0, 0, 0);
      oB1 = __builtin_amdgcn_mfma_f32_32x32x16_bf16(vS[4 + s], pf, oB1, 0, 0, 0);
    }
    __builtin_amdgcn_s_setprio(0);

    // reload V for t+1 (use at PV-A(t+1): gap = QK-A + SM-A)
    if (t < 31) {
      const u16* vt = vg + (size_t)(t + 1) * 4096;
#pragma unroll
      for (int i = 0; i < 8; ++i) vS[i] = *(const short8*)(vt + i * 512 + lo);
    }
  }

  // lsum per sub-problem: own-h 32 kv rows + other h via one shuffle
  float lA = (psA[0] + psA[1]) + (psA[2] + psA[3]);
  lA += __shfl_xor(lA, 32);
  float lB = (psB[0] + psB[1]) + (psB[2] + psB[3]);
  lB += __shfl_xor(lB, 32);
  const float invA = 1.0f / lA, invB = 1.0f / lB;

  // O^T: lane owns column q; rows d = 32*dblk + 8g + 4h + {0..3}
  u16* outp = attnout + ((size_t)(b * SEQ + tokenA)) * MODELD + hh * HDIM;
#pragma unroll
  for (int dblk = 0; dblk < 2; ++dblk) {
#pragma unroll
    for (int g = 0; g < 4; ++g) {
      float a0, a1, a2, a3, b0, b1, b2, b3;
      if (dblk == 0) {
        a0 = oA0[4 * g + 0]; a1 = oA0[4 * g + 1]; a2 = oA0[4 * g + 2]; a3 = oA0[4 * g + 3];
        b0 = oB0[4 * g + 0]; b1 = oB0[4 * g + 1]; b2 = oB0[4 * g + 2]; b3 = oB0[4 * g + 3];
      } else {
        a0 = oA1[4 * g + 0]; a1 = oA1[4 * g + 1]; a2 = oA1[4 * g + 2]; a3 = oA1[4 * g + 3];
        b0 = oB1[4 * g + 0]; b1 = oB1[4 * g + 1]; b2 = oB1[4 * g + 2]; b3 = oB1[4 * g + 3];
      }
      u32x2 ow;
      ow[0] = cvtpk(a0 * invA, a1 * invA);
      ow[1] = cvtpk(a2 * invA, a3 * invA);
      *(u32x2*)(outp + dblk * 32 + g * 8 + h * 4) = ow;
      u32x2 ob;
      ob[0] = cvtpk(b0 * invB, b1 * invB);
      ob[1] = cvtpk(b2 * invB, b3 * invB);
      *(u32x2*)(outp + 32 * MODELD + dblk * 32 + g * 8 + h * 4) = ob;
    }
  }
}

// ---------------- launch ----------------
extern "C" void kernel_launch(void* const* d_in, const int* in_sizes, int n_in,
                              void* d_out, int out_size, void* d_ws, size_t ws_size,
                              hipStream_t stream) {
  const float* x       = (const float*)d_in[0];
  const unsigned int* mask = (const unsigned int*)d_in[1];
  const float* w_qkv   = (const float*)d_in[2];
  const float* wq_base = (const float*)d_in[3];
  const float* bq      = (const float*)d_in[4];
  const float* wq_A    = (const float*)d_in[5];
  const float* wq_B    = (const float*)d_in[6];
  const float* wv_base = (const float*)d_in[7];
  const float* bv      = (const float*)d_in[8];
  const float* wv_A    = (const float*)d_in[9];
  const float* wv_B    = (const float*)d_in[10];
  const float* w_out   = (const float*)d_in[11];
  const float* b_out   = (const float*)d_in[12];
  float* out = (float*)d_out;

  char* ws = (char*)d_ws;
  u16* xb      = (u16*)(ws);                 // 8 MB  (reused as attnout)
  u16* wcomb   = (u16*)(ws + 8388608);       // 6 MB
  u16* woutb   = (u16*)(ws + 14680064);      // 2 MB
  u16* qws     = (u16*)(ws + 16777216);      // 8 MB  (row-major)
  u16* kws     = (u16*)(ws + 25165824);      // 8 MB  (frag-major)
  u16* vws     = (u16*)(ws + 33554432);      // 8 MB  (frag-major)
  float* biasc = (float*)(ws + 50331648);    // 12 KB
  u16* mbf     = (u16*)(ws + 50343936);      // 8 KB (bf16 0 / -256 K-ext values)
  u16* attnout = xb;                          // xb dead after gemm_qkv

  prep_cast<<<4096, 256, 0, stream>>>(x, xb);          // 4M elems
  prep_cast<<<1024, 256, 0, stream>>>(w_out, woutb);   // 1M elems
  prep_mask<<<1, 1024, 0, stream>>>(mask, mbf);
  prep_w<<<3072, 256, 0, stream>>>(w_qkv, wq_base, bq, wq_A, wq_B,
                                   wv_base, bv, wv_A, wv_B, wcomb, biasc);

  gemm128<0><<<dim3(QKVCOLS / 128, MROWS / 128), 256, 0, stream>>>(
      xb, wcomb, biasc, qws, kws, vws, nullptr);

  flash_attn<<<1024, 64, 0, stream>>>(qws, kws, vws, mbf, attnout);

  gemm128<1><<<dim3(MODELD / 128, MROWS / 128), 256, 0, stream>>>(
      attnout, woutb, b_out, nullptr, nullptr, nullptr, out);
}